// Round 1
// baseline (770.242 us; speedup 1.0000x reference)
//
#include <hip/hip_runtime.h>
#include <hip/hip_bf16.h>

// DisentangledSelfAttention: B=4096, S=64, E=64, A=256, H=4, HD=64.
// One block per batch b; 4 waves; wave w owns output rows 16w..16w+15.
// Heads processed sequentially through a shared LDS working set.
// Numerics: bq/bk cancel under mean-centering, bu cancels in softmax(axis=1)
// -> d_in[4], d_in[6], d_in[10] are provably unused.

#define B_ 4096
#define S_ 64
#define E_ 64
#define A_ 256
#define H_ 4

typedef __attribute__((ext_vector_type(8))) short bf16x8;
typedef __attribute__((ext_vector_type(4))) float f32x4;
typedef __attribute__((ext_vector_type(4))) short s16x4;

#define MFMA16(a, b, c) __builtin_amdgcn_mfma_f32_16x16x32_bf16((a), (b), (c), 0, 0, 0)

static __device__ __forceinline__ short f2b(float f) {  // RNE fp32->bf16
  union { float f; unsigned u; } x; x.f = f;
  unsigned r = x.u + 0x7fffu + ((x.u >> 16) & 1u);
  return (short)(r >> 16);
}
static __device__ __forceinline__ float b2f(short s) {
  union { unsigned u; float f; } x; x.u = ((unsigned)(unsigned short)s) << 16;
  return x.f;
}

// ws layout (units: shorts). Transposed bf16 weights WT[a][e] for B-fragments.
#define WQHI 0
#define WQLO 16384
#define WKHI 32768
#define WKLO 49152
#define WVT  65536
#define WRT  81920
#define WUT  98304   // [16][64], rows a<4 valid, else 0
// total 99328 shorts = 198656 bytes of d_ws

__global__ __launch_bounds__(256)
void prepass(const float* __restrict__ Wq, const float* __restrict__ Wk,
             const float* __restrict__ Wv, const float* __restrict__ Wr,
             const float* __restrict__ Wu, short* __restrict__ ws) {
  int t = blockIdx.x * 256 + threadIdx.x;  // 0..16383 -> (a, e)
  int a = t >> 6, e = t & 63;
  float wq = Wq[e * A_ + a]; short h = f2b(wq);
  ws[WQHI + t] = h; ws[WQLO + t] = f2b(wq - b2f(h));
  float wk = Wk[e * A_ + a]; h = f2b(wk);
  ws[WKHI + t] = h; ws[WKLO + t] = f2b(wk - b2f(h));
  ws[WVT + t] = f2b(Wv[e * A_ + a]);
  ws[WRT + t] = f2b(Wr[e * A_ + a]);
  if (t < 1024) {
    int a2 = t >> 6, e2 = t & 63;
    ws[WUT + t] = (a2 < 4) ? f2b(Wu[e2 * 4 + a2]) : (short)0;
  }
}

static __device__ __forceinline__ void load_split(const float* p, bf16x8& hi, bf16x8& lo) {
  f32x4 a0 = *(const f32x4*)p;
  f32x4 a1 = *(const f32x4*)(p + 4);
#pragma unroll
  for (int j = 0; j < 4; ++j) {
    short h0 = f2b(a0[j]); hi[j] = h0; lo[j] = f2b(a0[j] - b2f(h0));
    short h1 = f2b(a1[j]); hi[4 + j] = h1; lo[4 + j] = f2b(a1[j] - b2f(h1));
  }
}
static __device__ __forceinline__ void load_single(const float* p, bf16x8& hi) {
  f32x4 a0 = *(const f32x4*)p;
  f32x4 a1 = *(const f32x4*)(p + 4);
#pragma unroll
  for (int j = 0; j < 4; ++j) { hi[j] = f2b(a0[j]); hi[4 + j] = f2b(a1[j]); }
}

__global__ __launch_bounds__(256, 3)
void attn_main(const float* __restrict__ query, const float* __restrict__ key_,
               const float* __restrict__ value, const float* __restrict__ bv,
               const float* __restrict__ br, const short* __restrict__ ws,
               float* __restrict__ out) {
  const int b    = blockIdx.x;
  const int tid  = threadIdx.x;
  const int w    = tid >> 6;    // wave id = M-tile
  const int lane = tid & 63;
  const int quad = lane >> 4;
  const int lc   = lane & 15;

  __shared__ short Kb[64][72];   // centered K (bf16), row-major [s_k][hd(+head off removed)]
  __shared__ short Qb[64][72];   // centered Q; re-aliased as P (attn) after QK
  __shared__ short VT[64][72];   // V transposed [d][key]
  __shared__ float colsK[4][64];
  __shared__ float colsQ[4][64];
  __shared__ float u_lds[64 * 4];  // unary softmax [key][h]

  // ---- per-wave X fragments (A-operand rows 16w+lc), loaded once ----
  const size_t xoff = ((size_t)b * S_ + 16 * w + lc) * E_ + quad * 8;
  bf16x8 xq_hi[2], xq_lo[2], xk_hi[2], xk_lo[2], xv[2];
  load_split(query + xoff,      xq_hi[0], xq_lo[0]);
  load_split(query + xoff + 32, xq_hi[1], xq_lo[1]);
  load_split(key_  + xoff,      xk_hi[0], xk_lo[0]);
  load_split(key_  + xoff + 32, xk_hi[1], xk_lo[1]);
  load_single(value + xoff,      xv[0]);
  load_single(value + xoff + 32, xv[1]);

  for (int h = 0; h < H_; ++h) {
    // ---- K and Q projections, 3-term hi/lo (bias cancels under centering) ----
    f32x4 aK[4], aQ[4];
#pragma unroll
    for (int nt = 0; nt < 4; ++nt) {
      aK[nt] = f32x4{0.f, 0.f, 0.f, 0.f};
      aQ[nt] = f32x4{0.f, 0.f, 0.f, 0.f};
      const int arow = (h * 64 + nt * 16 + lc) * 64 + quad * 8;
#pragma unroll
      for (int kk = 0; kk < 2; ++kk) {
        bf16x8 bkh = *(const bf16x8*)(ws + WKHI + arow + kk * 32);
        bf16x8 bkl = *(const bf16x8*)(ws + WKLO + arow + kk * 32);
        aK[nt] = MFMA16(xk_hi[kk], bkh, aK[nt]);
        aK[nt] = MFMA16(xk_hi[kk], bkl, aK[nt]);
        aK[nt] = MFMA16(xk_lo[kk], bkh, aK[nt]);
        bf16x8 bqh = *(const bf16x8*)(ws + WQHI + arow + kk * 32);
        bf16x8 bql = *(const bf16x8*)(ws + WQLO + arow + kk * 32);
        aQ[nt] = MFMA16(xq_hi[kk], bqh, aQ[nt]);
        aQ[nt] = MFMA16(xq_hi[kk], bql, aQ[nt]);
        aQ[nt] = MFMA16(xq_lo[kk], bqh, aQ[nt]);
      }
    }
    // unary logits key_@Wu (once per block); bu cancels in softmax
    f32x4 aU = f32x4{0.f, 0.f, 0.f, 0.f};
    if (h == 0) {
#pragma unroll
      for (int kk = 0; kk < 2; ++kk) {
        bf16x8 bu8 = *(const bf16x8*)(ws + WUT + lc * 64 + kk * 32 + quad * 8);
        aU = MFMA16(xk_hi[kk], bu8, aU);
      }
    }
    // column partial sums for mean-centering (16 rows per wave)
#pragma unroll
    for (int nt = 0; nt < 4; ++nt) {
      float rk = aK[nt][0] + aK[nt][1] + aK[nt][2] + aK[nt][3];
      rk += __shfl_xor(rk, 16, 64); rk += __shfl_xor(rk, 32, 64);
      float rq = aQ[nt][0] + aQ[nt][1] + aQ[nt][2] + aQ[nt][3];
      rq += __shfl_xor(rq, 16, 64); rq += __shfl_xor(rq, 32, 64);
      if (lane < 16) { colsK[w][nt * 16 + lane] = rk; colsQ[w][nt * 16 + lane] = rq; }
    }
    if (h == 0 && lc < 4) {
#pragma unroll
      for (int r = 0; r < 4; ++r) u_lds[(16 * w + quad * 4 + r) * 4 + lc] = aU[r];
    }
    __syncthreads();  // barrier A: col-sums + raw unary ready; guards LDS reuse

    // ---- center and write K,Q as bf16 ----
#pragma unroll
    for (int nt = 0; nt < 4; ++nt) {
      const int c = nt * 16 + lc;
      float mK = (colsK[0][c] + colsK[1][c] + colsK[2][c] + colsK[3][c]) * (1.0f / 64.0f);
      float mQ = (colsQ[0][c] + colsQ[1][c] + colsQ[2][c] + colsQ[3][c]) * (1.0f / 64.0f);
#pragma unroll
      for (int r = 0; r < 4; ++r) {
        int row = 16 * w + quad * 4 + r;
        Kb[row][c] = f2b(aK[nt][r] - mK);
        Qb[row][c] = f2b(aQ[nt][r] - mQ);
      }
    }
    if (h == 0 && tid < 4) {  // unary softmax over fields, per head column
      float m = -1e30f;
      for (int s = 0; s < 64; ++s) m = fmaxf(m, u_lds[s * 4 + tid]);
      float sum = 0.f;
      for (int s = 0; s < 64; ++s) {
        float e = __expf(u_lds[s * 4 + tid] - m);
        u_lds[s * 4 + tid] = e; sum += e;
      }
      float inv = 1.0f / sum;
      for (int s = 0; s < 64; ++s) u_lds[s * 4 + tid] *= inv;
    }
    // ---- V projection (single bf16) + bias, written transposed [d][key] ----
#pragma unroll
    for (int nt = 0; nt < 4; ++nt) {
      f32x4 aV = f32x4{0.f, 0.f, 0.f, 0.f};
      const int arow = (h * 64 + nt * 16 + lc) * 64 + quad * 8;
#pragma unroll
      for (int kk = 0; kk < 2; ++kk) {
        bf16x8 bw = *(const bf16x8*)(ws + WVT + arow + kk * 32);
        aV = MFMA16(xv[kk], bw, aV);
      }
      float bvv = bv[h * 64 + nt * 16 + lc];
      s16x4 pk;
#pragma unroll
      for (int r = 0; r < 4; ++r) pk[r] = f2b(aV[r] + bvv);
      *(s16x4*)&VT[nt * 16 + lc][16 * w + quad * 4] = pk;
    }
    __syncthreads();  // barrier B: Kb, Qb, VT, u ready

    // ---- QK^T (unscaled) ----
    bf16x8 qa[2];
    qa[0] = *(const bf16x8*)&Qb[16 * w + lc][quad * 8];
    qa[1] = *(const bf16x8*)&Qb[16 * w + lc][32 + quad * 8];
    f32x4 L[4];
#pragma unroll
    for (int nt = 0; nt < 4; ++nt) {
      L[nt] = f32x4{0.f, 0.f, 0.f, 0.f};
#pragma unroll
      for (int kk = 0; kk < 2; ++kk) {
        bf16x8 kb = *(const bf16x8*)&Kb[nt * 16 + lc][kk * 32 + quad * 8];
        L[nt] = MFMA16(qa[kk], kb, L[nt]);
      }
    }
    // ---- row softmax + unary add; P overwrites Qb (own rows only) ----
#pragma unroll
    for (int r = 0; r < 4; ++r) {
      float m = fmaxf(fmaxf(L[0][r], L[1][r]), fmaxf(L[2][r], L[3][r]));
      m = fmaxf(m, __shfl_xor(m, 1, 64));
      m = fmaxf(m, __shfl_xor(m, 2, 64));
      m = fmaxf(m, __shfl_xor(m, 4, 64));
      m = fmaxf(m, __shfl_xor(m, 8, 64));
      float e0 = __expf(L[0][r] - m), e1 = __expf(L[1][r] - m);
      float e2 = __expf(L[2][r] - m), e3 = __expf(L[3][r] - m);
      float s = e0 + e1 + e2 + e3;
      s += __shfl_xor(s, 1, 64); s += __shfl_xor(s, 2, 64);
      s += __shfl_xor(s, 4, 64); s += __shfl_xor(s, 8, 64);
      float inv = __builtin_amdgcn_rcpf(s);
      int row = 16 * w + quad * 4 + r;
      Qb[row][lc]      = f2b(e0 * inv + u_lds[(lc)*4 + h]);
      Qb[row][16 + lc] = f2b(e1 * inv + u_lds[(16 + lc) * 4 + h]);
      Qb[row][32 + lc] = f2b(e2 * inv + u_lds[(32 + lc) * 4 + h]);
      Qb[row][48 + lc] = f2b(e3 * inv + u_lds[(48 + lc) * 4 + h]);
    }
    // ---- PV + residual (query@Wr, 2-term) + output ----
    // Same-wave DS write->read: DS ops are in-order within a wave; compiler lgkmcnt covers data dep.
    bf16x8 pa[2];
    pa[0] = *(const bf16x8*)&Qb[16 * w + lc][quad * 8];
    pa[1] = *(const bf16x8*)&Qb[16 * w + lc][32 + quad * 8];
#pragma unroll
    for (int nt = 0; nt < 4; ++nt) {
      f32x4 O = f32x4{0.f, 0.f, 0.f, 0.f};
      const int arow = (h * 64 + nt * 16 + lc) * 64 + quad * 8;
#pragma unroll
      for (int kk = 0; kk < 2; ++kk) {
        bf16x8 vb = *(const bf16x8*)&VT[nt * 16 + lc][kk * 32 + quad * 8];
        O = MFMA16(pa[kk], vb, O);
        bf16x8 wr = *(const bf16x8*)(ws + WRT + arow + kk * 32);
        O = MFMA16(xq_hi[kk], wr, O);
        O = MFMA16(xq_lo[kk], wr, O);
      }
      float brv = br[h * 64 + nt * 16 + lc];
      float* op = out + ((size_t)b * S_ + 16 * w + quad * 4) * A_ + h * 64 + nt * 16 + lc;
#pragma unroll
      for (int r = 0; r < 4; ++r) op[(size_t)r * A_] = O[r] + brv;
    }
  }
}

extern "C" void kernel_launch(void* const* d_in, const int* in_sizes, int n_in,
                              void* d_out, int out_size, void* d_ws, size_t ws_size,
                              hipStream_t stream) {
  (void)in_sizes; (void)n_in; (void)out_size; (void)ws_size;
  const float* query = (const float*)d_in[0];
  const float* key_  = (const float*)d_in[1];
  const float* value = (const float*)d_in[2];
  const float* Wq    = (const float*)d_in[3];
  // d_in[4] = bq: cancels under mean-centering
  const float* Wk    = (const float*)d_in[5];
  // d_in[6] = bk: cancels under mean-centering
  const float* Wv    = (const float*)d_in[7];
  const float* bv    = (const float*)d_in[8];
  const float* Wu    = (const float*)d_in[9];
  // d_in[10] = bu: cancels in softmax over fields
  const float* Wr    = (const float*)d_in[11];
  const float* br    = (const float*)d_in[12];
  short* ws = (short*)d_ws;

  hipLaunchKernelGGL(prepass, dim3(64), dim3(256), 0, stream, Wq, Wk, Wv, Wr, Wu, ws);
  hipLaunchKernelGGL(attn_main, dim3(B_), dim3(256), 0, stream,
                     query, key_, value, bv, br, ws, (float*)d_out);
}

// Round 2
// 565.254 us; speedup vs baseline: 1.3626x; 1.3626x over previous
//
#include <hip/hip_runtime.h>
#include <hip/hip_bf16.h>

// DisentangledSelfAttention: B=4096, S=64, E=64, A=256, H=4, HD=64.
// Head-per-wave, barrier-free main phase.
// Key algebra: centering over fields commutes with projection:
//   L_h = (C Xq) (Wq_h Wk_h^T) (C Xk)^T  with M_h = Wq_h Wk_h^T precomputed.
// bq/bk cancel under centering; bu cancels in softmax(axis=1);
// residual query@Wr = Xcq@Wr + 1*(mu_q^T Wr)  (rank-1 correction rho).

#define B_ 4096
#define H_ 4

typedef __attribute__((ext_vector_type(8))) short bf16x8;
typedef __attribute__((ext_vector_type(4))) float f32x4;
typedef __attribute__((ext_vector_type(4))) short s16x4;

#define MFMA16(a, b, c) __builtin_amdgcn_mfma_f32_16x16x32_bf16((a), (b), (c), 0, 0, 0)

static __device__ __forceinline__ short f2b(float f) {  // RNE fp32->bf16
  union { float f; unsigned u; } x; x.f = f;
  unsigned r = x.u + 0x7fffu + ((x.u >> 16) & 1u);
  return (short)(r >> 16);
}
static __device__ __forceinline__ float b2f(short s) {
  union { unsigned u; float f; } x; x.u = ((unsigned)(unsigned short)s) << 16;
  return x.f;
}

// ws layout (units: shorts)
#define MTHI 0       // [h][e'][e] = hi(M_h[e][e']), M = Wq_h Wk_h^T   (4*64*64)
#define MTLO 16384   // lo part
#define WVT  32768   // [a][e] = Wv[e][a]
#define WRT  49152   // [a][e] = Wr[e][a]
#define WU0  65536   // [h][16][64], row m=0 = Wu[:,h], rows 1..15 = 0
// total 69632 shorts = 139264 bytes

__global__ __launch_bounds__(256)
void prepass(const float* __restrict__ Wq, const float* __restrict__ Wk,
             const float* __restrict__ Wv, const float* __restrict__ Wr,
             const float* __restrict__ Wu, short* __restrict__ ws) {
  int t = blockIdx.x * 256 + threadIdx.x;  // 0..16383
  int a = t >> 6, e = t & 63;
  ws[WVT + t] = f2b(Wv[e * 256 + a]);
  ws[WRT + t] = f2b(Wr[e * 256 + a]);
  if (t < 4096) {
    int h = t >> 10, m = (t >> 6) & 15, e2 = t & 63;
    ws[WU0 + t] = (m == 0) ? f2b(Wu[e2 * 4 + h]) : (short)0;
  }
  // M_h[e][e'] = sum_a Wq[e, h*64+a] * Wk[e', h*64+a], stored transposed [e'][e]
  int h = t >> 12, ep = (t >> 6) & 63;
  const float* wqr = Wq + e * 256 + h * 64;
  const float* wkr = Wk + ep * 256 + h * 64;
  float s = 0.f;
#pragma unroll 8
  for (int aa = 0; aa < 64; ++aa) s += wqr[aa] * wkr[aa];
  short hi = f2b(s);
  ws[MTHI + (h * 64 + ep) * 64 + e] = hi;
  ws[MTLO + (h * 64 + ep) * 64 + e] = f2b(s - b2f(hi));
}

__global__ __launch_bounds__(256, 2)
void attn_main(const float* __restrict__ query, const float* __restrict__ key_,
               const float* __restrict__ value, const float* __restrict__ bv,
               const float* __restrict__ br, const short* __restrict__ ws,
               float* __restrict__ out) {
  const int b    = blockIdx.x;
  const int tid  = threadIdx.x;
  const int w    = tid >> 6;    // wave id == head id
  const int lane = tid & 63;
  const int quad = lane >> 4;
  const int lc   = lane & 15;
  const int h    = w;

  __shared__ short XqH[64][72];     // centered query, hi bf16
  __shared__ short XqL[64][72];     // centered query, lo bf16
  __shared__ short Xk [64][72];     // centered key, single bf16
  __shared__ short buf[4][64][72];  // per-wave scratch: T -> VT -> P
  __shared__ float colsq[4][64];
  __shared__ float colsk[4][64];
  __shared__ float mq[64];          // query column means (for rho)

  // ================= centering phase (2 barriers, then barrier-free) ========
  const int crow = w * 16 + (lane >> 2);   // row this lane loads
  const int cg   = (lane & 3) * 16;        // col group base
  const float* qp = query + ((size_t)b * 64 + crow) * 64 + cg;
  const float* kp = key_  + ((size_t)b * 64 + crow) * 64 + cg;
  f32x4 qv[4], kv[4];
#pragma unroll
  for (int j = 0; j < 4; ++j) { qv[j] = *(const f32x4*)(qp + 4 * j); kv[j] = *(const f32x4*)(kp + 4 * j); }

  // partial column sums over this wave's 16 rows (rows live at lane bits 2..5)
  f32x4 sq[4], sk[4];
#pragma unroll
  for (int j = 0; j < 4; ++j) { sq[j] = qv[j]; sk[j] = kv[j]; }
#pragma unroll
  for (int off = 4; off <= 32; off <<= 1)
#pragma unroll
    for (int j = 0; j < 4; ++j)
#pragma unroll
      for (int c = 0; c < 4; ++c) {
        sq[j][c] += __shfl_xor(sq[j][c], off);
        sk[j][c] += __shfl_xor(sk[j][c], off);
      }
  if ((lane & 60) == 0) {  // lanes 0..3, one per col group
#pragma unroll
    for (int j = 0; j < 4; ++j) {
      *(f32x4*)&colsq[w][cg + 4 * j] = sq[j];
      *(f32x4*)&colsk[w][cg + 4 * j] = sk[j];
    }
  }
  __syncthreads();  // barrier 1: partial sums visible

  f32x4 mqv[4], mkv[4];
#pragma unroll
  for (int j = 0; j < 4; ++j) {
    f32x4 aq = {0.f, 0.f, 0.f, 0.f}, ak = {0.f, 0.f, 0.f, 0.f};
#pragma unroll
    for (int ww = 0; ww < 4; ++ww) {
      aq += *(const f32x4*)&colsq[ww][cg + 4 * j];
      ak += *(const f32x4*)&colsk[ww][cg + 4 * j];
    }
    mqv[j] = aq * (1.0f / 64.0f);
    mkv[j] = ak * (1.0f / 64.0f);
  }
  if (w == 0 && (lane & 60) == 0)
#pragma unroll
    for (int j = 0; j < 4; ++j) *(f32x4*)&mq[cg + 4 * j] = mqv[j];

  // center, split hi/lo, store to shared LDS
#pragma unroll
  for (int half = 0; half < 2; ++half) {
    bf16x8 qh8, ql8, k8;
#pragma unroll
    for (int jj = 0; jj < 8; ++jj) {
      int j = half * 2 + (jj >> 2), c = jj & 3;
      float cq = qv[j][c] - mqv[j][c];
      short hi = f2b(cq);
      qh8[jj] = hi;
      ql8[jj] = f2b(cq - b2f(hi));
      k8[jj]  = f2b(kv[j][c] - mkv[j][c]);
    }
    *(bf16x8*)&XqH[crow][cg + 8 * half] = qh8;
    *(bf16x8*)&XqL[crow][cg + 8 * half] = ql8;
    *(bf16x8*)&Xk [crow][cg + 8 * half] = k8;
  }
  __syncthreads();  // barrier 2: Xc buffers + mq visible. No more barriers.

  // ================= per-head phase (wave-private) ==========================
  // rho[d=lane] = mu_q . Wr[:, h*64+lane] + br[h*64+lane]
  float rho;
  {
    const short* wrr = ws + WRT + (h * 64 + lane) * 64;
    float acc = br[h * 64 + lane];
#pragma unroll
    for (int e8 = 0; e8 < 8; ++e8) {
      bf16x8 w8 = *(const bf16x8*)(wrr + e8 * 8);
#pragma unroll
      for (int j = 0; j < 8; ++j) acc += mq[e8 * 8 + j] * b2f(w8[j]);
    }
    rho = acc;
  }

  // value A-fragments (uncentered, single bf16) straight from global
  bf16x8 xv[4][2];
#pragma unroll
  for (int mt = 0; mt < 4; ++mt)
#pragma unroll
    for (int kk = 0; kk < 2; ++kk) {
      const float* vp = value + ((size_t)b * 64 + mt * 16 + lc) * 64 + kk * 32 + quad * 8;
      f32x4 v0 = *(const f32x4*)vp, v1 = *(const f32x4*)(vp + 4);
#pragma unroll
      for (int j = 0; j < 4; ++j) { xv[mt][kk][j] = f2b(v0[j]); xv[mt][kk][4 + j] = f2b(v1[j]); }
    }

  // ---- unary: u = softmax_s( Xck @ Wu[:,h] )  (uniform shift cancels) ----
  float usm[4];
  {
    bf16x8 wu[2];
#pragma unroll
    for (int kk = 0; kk < 2; ++kk)
      wu[kk] = *(const bf16x8*)(ws + WU0 + h * 1024 + lc * 64 + kk * 32 + quad * 8);
    f32x4 aU[4];
#pragma unroll
    for (int nt = 0; nt < 4; ++nt) {
      aU[nt] = f32x4{0.f, 0.f, 0.f, 0.f};
#pragma unroll
      for (int kk = 0; kk < 2; ++kk) {
        bf16x8 xb = *(const bf16x8*)&Xk[nt * 16 + lc][kk * 32 + quad * 8];
        aU[nt] = MFMA16(wu[kk], xb, aU[nt]);
      }
    }
    float un[4];
#pragma unroll
    for (int nt = 0; nt < 4; ++nt) un[nt] = __shfl(aU[nt][0], lc);  // u[nt*16+lc]
    float um = fmaxf(fmaxf(un[0], un[1]), fmaxf(un[2], un[3]));
    um = fmaxf(um, __shfl_xor(um, 1)); um = fmaxf(um, __shfl_xor(um, 2));
    um = fmaxf(um, __shfl_xor(um, 4)); um = fmaxf(um, __shfl_xor(um, 8));
    float ue[4], us = 0.f;
#pragma unroll
    for (int nt = 0; nt < 4; ++nt) { ue[nt] = __expf(un[nt] - um); us += ue[nt]; }
    us += __shfl_xor(us, 1); us += __shfl_xor(us, 2);
    us += __shfl_xor(us, 4); us += __shfl_xor(us, 8);
    float uinv = __builtin_amdgcn_rcpf(us);
#pragma unroll
    for (int nt = 0; nt < 4; ++nt) usm[nt] = ue[nt] * uinv;
  }

  // ---- T = Xcq @ M_h  (3-term hi/lo, near-fp32) -> buf (as bf16) ----
  {
    bf16x8 mh[4][2], ml[4][2];
#pragma unroll
    for (int nt = 0; nt < 4; ++nt)
#pragma unroll
      for (int kk = 0; kk < 2; ++kk) {
        int off = h * 4096 + (nt * 16 + lc) * 64 + kk * 32 + quad * 8;
        mh[nt][kk] = *(const bf16x8*)(ws + MTHI + off);
        ml[nt][kk] = *(const bf16x8*)(ws + MTLO + off);
      }
    f32x4 aT[4][4];
#pragma unroll
    for (int mt = 0; mt < 4; ++mt) {
      bf16x8 xh[2], xl[2];
#pragma unroll
      for (int kk = 0; kk < 2; ++kk) {
        xh[kk] = *(const bf16x8*)&XqH[mt * 16 + lc][kk * 32 + quad * 8];
        xl[kk] = *(const bf16x8*)&XqL[mt * 16 + lc][kk * 32 + quad * 8];
      }
#pragma unroll
      for (int nt = 0; nt < 4; ++nt) {
        f32x4 acc = {0.f, 0.f, 0.f, 0.f};
#pragma unroll
        for (int kk = 0; kk < 2; ++kk) {
          acc = MFMA16(xh[kk], mh[nt][kk], acc);
          acc = MFMA16(xh[kk], ml[nt][kk], acc);
          acc = MFMA16(xl[kk], mh[nt][kk], acc);
        }
        aT[mt][nt] = acc;
      }
    }
    // store T (C-layout -> row-major [q][e'])
#pragma unroll
    for (int mt = 0; mt < 4; ++mt)
#pragma unroll
      for (int nt = 0; nt < 4; ++nt)
#pragma unroll
        for (int r = 0; r < 4; ++r)
          buf[w][mt * 16 + quad * 4 + r][nt * 16 + lc] = f2b(aT[mt][nt][r]);
  }

  // T A-fragments (held in regs; buf gets reused for VT next)
  bf16x8 tA[4][2];
#pragma unroll
  for (int mt = 0; mt < 4; ++mt)
#pragma unroll
    for (int kk = 0; kk < 2; ++kk)
      tA[mt][kk] = *(const bf16x8*)&buf[w][mt * 16 + lc][kk * 32 + quad * 8];

  // ---- V = Xv @ Wv_h + bv -> buf as V^T[d][key] ----
#pragma unroll
  for (int mt = 0; mt < 4; ++mt) {
#pragma unroll
    for (int nt = 0; nt < 4; ++nt) {
      f32x4 acc = {0.f, 0.f, 0.f, 0.f};
#pragma unroll
      for (int kk = 0; kk < 2; ++kk) {
        bf16x8 wv8 = *(const bf16x8*)(ws + WVT + (h * 64 + nt * 16 + lc) * 64 + kk * 32 + quad * 8);
        acc = MFMA16(xv[mt][kk], wv8, acc);
      }
      float bvv = bv[h * 64 + nt * 16 + lc];
      s16x4 pk;
#pragma unroll
      for (int r = 0; r < 4; ++r) pk[r] = f2b(acc[r] + bvv);
      *(s16x4*)&buf[w][nt * 16 + lc][mt * 16 + quad * 4] = pk;  // VT[d][key]
    }
  }
  // V^T B-fragments (held in regs; buf gets reused for P next)
  bf16x8 vB[4][2];
#pragma unroll
  for (int nt = 0; nt < 4; ++nt)
#pragma unroll
    for (int kk = 0; kk < 2; ++kk)
      vB[nt][kk] = *(const bf16x8*)&buf[w][nt * 16 + lc][kk * 32 + quad * 8];

  // ---- L = T @ Xck^T ----
  f32x4 aL[4][4];
  {
    bf16x8 xkB[4][2];
#pragma unroll
    for (int nt = 0; nt < 4; ++nt)
#pragma unroll
      for (int kk = 0; kk < 2; ++kk)
        xkB[nt][kk] = *(const bf16x8*)&Xk[nt * 16 + lc][kk * 32 + quad * 8];
#pragma unroll
    for (int mt = 0; mt < 4; ++mt)
#pragma unroll
      for (int nt = 0; nt < 4; ++nt) {
        f32x4 acc = {0.f, 0.f, 0.f, 0.f};
#pragma unroll
        for (int kk = 0; kk < 2; ++kk) acc = MFMA16(tA[mt][kk], xkB[nt][kk], acc);
        aL[mt][nt] = acc;
      }
  }

  // ---- row softmax + unary; P -> buf ----
#pragma unroll
  for (int mt = 0; mt < 4; ++mt)
#pragma unroll
    for (int r = 0; r < 4; ++r) {
      float m = fmaxf(fmaxf(aL[mt][0][r], aL[mt][1][r]), fmaxf(aL[mt][2][r], aL[mt][3][r]));
      m = fmaxf(m, __shfl_xor(m, 1)); m = fmaxf(m, __shfl_xor(m, 2));
      m = fmaxf(m, __shfl_xor(m, 4)); m = fmaxf(m, __shfl_xor(m, 8));
      float e0 = __expf(aL[mt][0][r] - m), e1 = __expf(aL[mt][1][r] - m);
      float e2 = __expf(aL[mt][2][r] - m), e3 = __expf(aL[mt][3][r] - m);
      float s = e0 + e1 + e2 + e3;
      s += __shfl_xor(s, 1); s += __shfl_xor(s, 2);
      s += __shfl_xor(s, 4); s += __shfl_xor(s, 8);
      float inv = __builtin_amdgcn_rcpf(s);
      int row = mt * 16 + quad * 4 + r;
      buf[w][row][lc]      = f2b(e0 * inv + usm[0]);
      buf[w][row][16 + lc] = f2b(e1 * inv + usm[1]);
      buf[w][row][32 + lc] = f2b(e2 * inv + usm[2]);
      buf[w][row][48 + lc] = f2b(e3 * inv + usm[3]);
    }

  // ---- out = P @ V + Xcq @ Wr_h (2-term) + rho ----
  bf16x8 pA[4][2];
#pragma unroll
  for (int mt = 0; mt < 4; ++mt)
#pragma unroll
    for (int kk = 0; kk < 2; ++kk)
      pA[mt][kk] = *(const bf16x8*)&buf[w][mt * 16 + lc][kk * 32 + quad * 8];

  float rr[4];
#pragma unroll
  for (int nt = 0; nt < 4; ++nt) rr[nt] = __shfl(rho, nt * 16 + lc);

#pragma unroll
  for (int mt = 0; mt < 4; ++mt) {
    bf16x8 xh[2], xl[2];
#pragma unroll
    for (int kk = 0; kk < 2; ++kk) {
      xh[kk] = *(const bf16x8*)&XqH[mt * 16 + lc][kk * 32 + quad * 8];
      xl[kk] = *(const bf16x8*)&XqL[mt * 16 + lc][kk * 32 + quad * 8];
    }
#pragma unroll
    for (int nt = 0; nt < 4; ++nt) {
      f32x4 acc = {0.f, 0.f, 0.f, 0.f};
#pragma unroll
      for (int kk = 0; kk < 2; ++kk) {
        acc = MFMA16(pA[mt][kk], vB[nt][kk], acc);
        bf16x8 wr8 = *(const bf16x8*)(ws + WRT + (h * 64 + nt * 16 + lc) * 64 + kk * 32 + quad * 8);
        acc = MFMA16(xh[kk], wr8, acc);
        acc = MFMA16(xl[kk], wr8, acc);
      }
      float* op = out + ((size_t)b * 64 + mt * 16 + quad * 4) * 256 + h * 64 + nt * 16 + lc;
#pragma unroll
      for (int r = 0; r < 4; ++r) op[(size_t)r * 256] = acc[r] + rr[nt];
    }
  }
}

extern "C" void kernel_launch(void* const* d_in, const int* in_sizes, int n_in,
                              void* d_out, int out_size, void* d_ws, size_t ws_size,
                              hipStream_t stream) {
  (void)in_sizes; (void)n_in; (void)out_size; (void)ws_size;
  const float* query = (const float*)d_in[0];
  const float* key_  = (const float*)d_in[1];
  const float* value = (const float*)d_in[2];
  const float* Wq    = (const float*)d_in[3];
  // d_in[4] = bq: cancels under mean-centering
  const float* Wk    = (const float*)d_in[5];
  // d_in[6] = bk: cancels under mean-centering
  const float* Wv    = (const float*)d_in[7];
  const float* bv    = (const float*)d_in[8];
  const float* Wu    = (const float*)d_in[9];
  // d_in[10] = bu: cancels in softmax over fields
  const float* Wr    = (const float*)d_in[11];
  const float* br    = (const float*)d_in[12];
  short* ws = (short*)d_ws;

  hipLaunchKernelGGL(prepass, dim3(64), dim3(256), 0, stream, Wq, Wk, Wv, Wr, Wu, ws);
  hipLaunchKernelGGL(attn_main, dim3(B_), dim3(256), 0, stream,
                     query, key_, value, bv, br, ws, (float*)d_out);
}